// Round 21
// baseline (176.970 us; speedup 1.0000x reference)
//
#include <hip/hip_runtime.h>
#include <stdint.h>

#define BATCH 8
#define NCLS 80
#define MAXDET 100
#define CAP 512
#define NBINS 10240          // keys 0..9012 (score 1.0) fit without clamping
#define TT 1024              // tail kernel threads
#define TCHUNK 10            // 1024 threads * 10 bins = 10240
#define BASEKEY (0x3D4CCCCDu >> 12)   // float bits of 0.05f >> 12

#define PR_ROWS 32           // rows per wave-group
#define PR_PAD 84            // floats per slab row (16B-aligned, ~4-way reads)
#define PR_WAVES 2           // waves per block (128 threads)
#define PR_BLOCKS 768        // 3 resident/CU (LDS-capped), grid-stride

// ---------------- Kernel 1: scores — double-buffered T14 pipeline ----------------
// Per wave, per iteration: [issue 10 contiguous float4 loads for group g+1]
// -> [compute group g from slab[cur] (bit-exact 2-lane float4 softmax)]
// -> [vmcnt wait lands HERE (compiler) + ds_write staged data to slab[1-cur]]
// -> swap. Loads stay in flight under compute; no barriers, waves independent.
__global__ __launch_bounds__(128, 1)
void scores_kernel(const float* __restrict__ cls,
                   float* __restrict__ scores, int BN) {
  __shared__ float slab_all[PR_WAVES * 2 * PR_ROWS * PR_PAD];  // 43 KB
  const int lane = threadIdx.x & 63;
  const int wid  = threadIdx.x >> 6;
  float* slabA = slab_all + (wid * 2 + 0) * (PR_ROWS * PR_PAD);
  float* slabB = slab_all + (wid * 2 + 1) * (PR_ROWS * PR_PAD);
  const int ngroups = (BN + PR_ROWS - 1) / PR_ROWS;   // BN%32==0 here
  const int wstride = gridDim.x * PR_WAVES;

  int g = blockIdx.x * PR_WAVES + wid;
  if (g >= ngroups) return;

  // lane's (row, pos) within a group for each of the 10 staged float4s
  int rr[10], pp[10];
#pragma unroll
  for (int k = 0; k < 10; k++) {
    int f = k * 64 + lane;
    rr[k] = f / 20; pp[k] = (f - rr[k] * 20) * 4;
  }

  // prologue: stage group g into slabA
  {
    const float4* src = (const float4*)(cls + (size_t)g * PR_ROWS * NCLS);
    float4 st[10];
#pragma unroll
    for (int k = 0; k < 10; k++) st[k] = src[k * 64 + lane];
#pragma unroll
    for (int k = 0; k < 10; k++) *(float4*)&slabA[rr[k] * PR_PAD + pp[k]] = st[k];
  }

  int cur = 0;
  while (true) {
    const int gn = g + wstride;

    // issue loads for next group early (stay in flight under compute)
    float4 st[10];
    const bool have_next = (gn < ngroups);
    if (have_next) {
      const float4* srcn = (const float4*)(cls + (size_t)gn * PR_ROWS * NCLS);
#pragma unroll
      for (int k = 0; k < 10; k++) st[k] = srcn[k * 64 + lane];
    }

    // compute group g from slab[cur]
    {
      float* slab = cur ? slabB : slabA;
      const int rt = lane >> 1;
      const int l = lane & 1;
      const float4* t4 = (const float4*)&slab[rt * PR_PAD];
      float4 v[10];
#pragma unroll
      for (int i = 0; i < 10; i++) v[i] = t4[l + 2 * i];

      float m = fmaxf(fmaxf(v[0].x, v[0].y), fmaxf(v[0].z, v[0].w));
#pragma unroll
      for (int i = 1; i < 10; i++)
        m = fmaxf(m, fmaxf(fmaxf(v[i].x, v[i].y), fmaxf(v[i].z, v[i].w)));
      m = fmaxf(m, __shfl_xor(m, 1));

      float a0 = 0.f, a1 = 0.f, a2 = 0.f, a3 = 0.f;
#pragma unroll
      for (int i = 0; i < 10; i++) {
        a0 += expf(v[i].x - m);
        a1 += expf(v[i].y - m);
        a2 += expf(v[i].z - m);
        a3 += expf(v[i].w - m);
      }
      float s_half = (a0 + a1) + (a2 + a3);
      float s = s_half + __shfl_xor(s_half, 1);
      if (l == 0) scores[g * PR_ROWS + rt] = 1.0f / s;
    }

    if (!have_next) break;

    // write-late: staged data -> other slab (vmcnt waits inserted here)
    {
      float* sl = cur ? slabA : slabB;
#pragma unroll
      for (int k = 0; k < 10; k++) *(float4*)&sl[rr[k] * PR_PAD + pp[k]] = st[k];
    }
    cur ^= 1;
    g = gn;
  }
}

// ---------------- Kernel 2: fused tail — one block per batch (R17, unchanged) ----
__global__ __launch_bounds__(TT)
void tail_kernel(const float* __restrict__ box, const float* __restrict__ cls,
                 const float* __restrict__ scores,
                 float* __restrict__ out, int N) {
  __shared__ uint32_t lh[NBINS];
  __shared__ uint32_t chs[TT];
  __shared__ unsigned long long sk[CAP];
  __shared__ float sbox[CAP][4];
  __shared__ uint32_t sidx[CAP];
  __shared__ float4 accb[MAXDET];
  __shared__ float4 accp[MAXDET];
  __shared__ uint32_t pick_i[MAXDET];
  __shared__ int T_sh, nacc_sh;
  __shared__ uint32_t lctr;

  const int b = blockIdx.x;
  const int tid = threadIdx.x;
  const float* sc = scores + (size_t)b * N;

#pragma unroll
  for (int j = 0; j < TCHUNK; j++) lh[tid + j * TT] = 0;
  if (tid < CAP) sk[tid] = 0ULL;
  if (tid == 0) { lctr = 0; T_sh = NBINS; }
  __syncthreads();

  const float4* sc4 = (const float4*)sc;
  const int N4 = N >> 2;
  for (int i = tid; i < N4; i += TT) {
    float4 v = sc4[i];
    if (v.x >= 0.05f) atomicAdd(&lh[(__float_as_uint(v.x) >> 12) - BASEKEY], 1u);
    if (v.y >= 0.05f) atomicAdd(&lh[(__float_as_uint(v.y) >> 12) - BASEKEY], 1u);
    if (v.z >= 0.05f) atomicAdd(&lh[(__float_as_uint(v.z) >> 12) - BASEKEY], 1u);
    if (v.w >= 0.05f) atomicAdd(&lh[(__float_as_uint(v.w) >> 12) - BASEKEY], 1u);
  }
  for (int i = (N4 << 2) + tid; i < N; i += TT) {
    float s = sc[i];
    if (s >= 0.05f) atomicAdd(&lh[(__float_as_uint(s) >> 12) - BASEKEY], 1u);
  }
  __syncthreads();

  uint32_t csum = 0;
#pragma unroll
  for (int j = 0; j < TCHUNK; j++) csum += lh[tid * TCHUNK + j];
  chs[tid] = csum;
  __syncthreads();
  for (int off = 1; off < TT; off <<= 1) {
    uint32_t v = chs[tid];
    uint32_t add = (tid + off < TT) ? chs[tid + off] : 0u;
    __syncthreads();
    chs[tid] = v + add;
    __syncthreads();
  }
  {
    uint32_t St = chs[tid];
    uint32_t Sprev = (tid > 0) ? chs[tid - 1] : 0xFFFFFFFFu;
    if (St <= CAP && (tid == 0 || Sprev > CAP)) {
      int T = 0;
      if (tid != 0) {
        uint32_t cum = St;
        int lo = (tid - 1) * TCHUNK;
        T = lo;
        for (int bb = tid * TCHUNK - 1; bb >= lo; bb--) {
          uint32_t nb = cum + lh[bb];
          if (nb > CAP) { T = bb + 1; break; }
          cum = nb;
          if (bb == lo) T = lo;
        }
      }
      T_sh = T;
    }
  }
  __syncthreads();
  const uint32_t T = (uint32_t)T_sh;

  for (int i = tid; i < N4; i += TT) {
    float4 v = sc4[i];
#pragma unroll
    for (int c = 0; c < 4; c++) {
      float s = (c == 0) ? v.x : (c == 1) ? v.y : (c == 2) ? v.z : v.w;
      if (s >= 0.05f) {
        uint32_t key = (__float_as_uint(s) >> 12) - BASEKEY;
        if (key >= T) {
          uint32_t slot = atomicAdd(&lctr, 1u);
          if (slot < CAP)
            sk[slot] = ((unsigned long long)__float_as_uint(s) << 32) |
                       (unsigned long long)(~(uint32_t)(i * 4 + c));
        }
      }
    }
  }
  for (int i = (N4 << 2) + tid; i < N; i += TT) {
    float s = sc[i];
    if (s >= 0.05f) {
      uint32_t key = (__float_as_uint(s) >> 12) - BASEKEY;
      if (key >= T) {
        uint32_t slot = atomicAdd(&lctr, 1u);
        if (slot < CAP)
          sk[slot] = ((unsigned long long)__float_as_uint(s) << 32) |
                     (unsigned long long)(~(uint32_t)i);
      }
    }
  }
  __syncthreads();
  uint32_t nc = lctr; if (nc > CAP) nc = CAP;

  for (int k = 2; k <= CAP; k <<= 1) {
    for (int j = k >> 1; j > 0; j >>= 1) {
      int i = tid;
      if (i < CAP) {
        int ixj = i ^ j;
        if (ixj > i) {
          unsigned long long a = sk[i], c = sk[ixj];
          if (((i & k) == 0) ? (a < c) : (a > c)) { sk[i] = c; sk[ixj] = a; }
        }
      }
      __syncthreads();
    }
  }

  if (tid < CAP) {
    unsigned long long k = sk[tid];
    uint32_t idx = (uint32_t)k ^ 0xFFFFFFFFu;
    sidx[tid] = idx;
    if (k != 0ULL) {
      const float4 f = *(const float4*)(box + ((size_t)b * N + idx) * 4);
      sbox[tid][0] = f.x; sbox[tid][1] = f.y;
      sbox[tid][2] = f.z - f.x; sbox[tid][3] = f.w - f.y;
    } else {
      sbox[tid][0] = 0.f; sbox[tid][1] = 0.f; sbox[tid][2] = 0.f; sbox[tid][3] = 0.f;
    }
  }
  __syncthreads();

  if (tid < 64) {
    const int lane = tid;
    int nacc = 0, nprop = 0;
    for (int cursor = 0; cursor < (int)nc && nacc < MAXDET; cursor += 64) {
      const int c = cursor + lane;
      bool alive = (c < (int)nc);
      float c0 = 0.f, c1 = 0.f, c2 = 0.f, c3 = 0.f;
      uint32_t myidx = 0;
      if (alive) {
        c0 = sbox[c][0]; c1 = sbox[c][1]; c2 = sbox[c][2]; c3 = sbox[c][3];
        myidx = sidx[c];
      }
      const float area_b = (c2 - c0) * (c3 - c1);

#pragma unroll 2
      for (int a = 0; a < nprop; a++) {
        float4 ar = accp[a];
        float area_r = (ar.z - ar.x) * (ar.w - ar.y);
        float ih = fmaxf(0.f, fminf(ar.z, c2) - fmaxf(ar.x, c0));
        float iw = fmaxf(0.f, fminf(ar.w, c3) - fmaxf(ar.y, c1));
        float inter = ih * iw;
        float uni = area_r + area_b - inter;
        bool okk = (area_r > 0.f) && (area_b > 0.f) && (uni > 0.f);
        float iou = okk ? (inter / uni) : 0.f;
        if (iou > 0.5f) alive = false;
      }

      unsigned long long am = __ballot(alive);
      while (am != 0ULL && nacc < MAXDET) {
        int L = (int)(__ffsll(am) - 1);
        float r0 = __shfl(c0, L), r1 = __shfl(c1, L);
        float r2 = __shfl(c2, L), r3 = __shfl(c3, L);
        uint32_t ridx = (uint32_t)__shfl((int)myidx, L);
        bool proper = (r2 > r0) && (r3 > r1);
        if (lane == 0) {
          pick_i[nacc] = ridx;
          accb[nacc] = make_float4(r0, r1, r2, r3);
          if (proper) accp[nprop] = make_float4(r0, r1, r2, r3);
        }
        asm volatile("s_waitcnt lgkmcnt(0)" ::: "memory");
        if (lane == L) alive = false;
        if (proper) {
          if (alive) {
            float area_r = (r2 - r0) * (r3 - r1);
            float ih = fmaxf(0.f, fminf(r2, c2) - fmaxf(r0, c0));
            float iw = fmaxf(0.f, fminf(r3, c3) - fmaxf(r1, c1));
            float inter = ih * iw;
            float uni = area_r + area_b - inter;
            bool okk = (area_r > 0.f) && (area_b > 0.f) && (uni > 0.f);
            float iou = okk ? (inter / uni) : 0.f;
            if (iou > 0.5f) alive = false;
          }
          nprop++;
        }
        am = __ballot(alive);
        nacc++;
      }
    }
    if (lane == 0) nacc_sh = nacc;
  }
  __syncthreads();

  const int nacc = nacc_sh;
  if (tid >= MAXDET) return;
  const int r = b * MAXDET + tid;
  float* boxes_out  = out;
  float* clsidx_out = out + BATCH * MAXDET * 4;
  float* cls_out    = out + BATCH * MAXDET * 4 + BATCH * MAXDET;

  if (tid >= nacc) {
    boxes_out[r * 4 + 0] = 0.f; boxes_out[r * 4 + 1] = 0.f;
    boxes_out[r * 4 + 2] = 0.f; boxes_out[r * 4 + 3] = 0.f;
    clsidx_out[r] = 0.f;
    for (int j = 0; j < NCLS; j++) cls_out[r * NCLS + j] = 0.f;
    return;
  }
  float4 bb = accb[tid];
  boxes_out[r * 4 + 0] = bb.x;
  boxes_out[r * 4 + 1] = bb.y;
  boxes_out[r * 4 + 2] = bb.z;
  boxes_out[r * 4 + 3] = bb.w;

  uint32_t idx = pick_i[tid];
  const float4* p = (const float4*)(cls + ((size_t)b * N + idx) * NCLS);
  float x[NCLS];
#pragma unroll
  for (int i = 0; i < NCLS / 4; i++) {
    float4 v = p[i];
    x[4 * i] = v.x; x[4 * i + 1] = v.y; x[4 * i + 2] = v.z; x[4 * i + 3] = v.w;
  }
  float m = x[0];
#pragma unroll
  for (int i = 1; i < NCLS; i++) m = fmaxf(m, x[i]);
  float r8[8];
#pragma unroll
  for (int j = 0; j < 8; j++) r8[j] = 0.0f;
#pragma unroll
  for (int i = 0; i < NCLS / 8; i++)
#pragma unroll
    for (int j = 0; j < 8; j++) r8[j] += expf(x[i * 8 + j] - m);
  float s = ((r8[0] + r8[1]) + (r8[2] + r8[3])) + ((r8[4] + r8[5]) + (r8[6] + r8[7]));

  float best = -1.f; int bi = 0;
  for (int j = 0; j < NCLS; j++) {
    float pj = expf(x[j] - m) / s;
    cls_out[r * NCLS + j] = pj;
    if (pj > best) { best = pj; bi = j; }
  }
  clsidx_out[r] = (float)bi;
}

extern "C" void kernel_launch(void* const* d_in, const int* in_sizes, int n_in,
                              void* d_out, int out_size, void* d_ws, size_t ws_size,
                              hipStream_t stream) {
  (void)n_in; (void)out_size; (void)ws_size;
  const float* box = (const float*)d_in[0];
  const float* cls = (const float*)d_in[1];
  const int N = in_sizes[0] / (BATCH * 4);
  const int BN = BATCH * N;

  float* ws_scores = (float*)d_ws;   // BN floats

  scores_kernel<<<PR_BLOCKS, 128, 0, stream>>>(cls, ws_scores, BN);
  tail_kernel<<<BATCH, TT, 0, stream>>>(box, cls, ws_scores, (float*)d_out, N);
}

// Round 22
// 116.736 us; speedup vs baseline: 1.5160x; 1.5160x over previous
//
#include <hip/hip_runtime.h>
#include <stdint.h>

#define BATCH 8
#define NCLS 80
#define MAXDET 100
#define CAP 512
#define NBINS 10240          // keys 0..9012 (score 1.0) fit without clamping
#define TT 1024              // tail kernel threads
#define TCHUNK 10            // 1024 threads * 10 bins = 10240
#define BASEKEY (0x3D4CCCCDu >> 12)   // float bits of 0.05f >> 12

// ---------------- Kernel 1: scores, 2 lanes per row, float4 loads, bit-exact ----
// (R17 form: best measured across 6 scores variants.)
__global__ __launch_bounds__(256)
void scores_kernel(const float* __restrict__ cls,
                   float* __restrict__ scores, int BN) {
  int gid = blockIdx.x * 256 + threadIdx.x;
  int row = gid >> 1;
  int l = gid & 1;
  if (row >= BN) return;
  const float4* p4 = (const float4*)(cls + (size_t)row * NCLS);

  float4 v[10];
#pragma unroll
  for (int i = 0; i < 10; i++) v[i] = p4[l + 2 * i];

  float m = fmaxf(fmaxf(v[0].x, v[0].y), fmaxf(v[0].z, v[0].w));
#pragma unroll
  for (int i = 1; i < 10; i++)
    m = fmaxf(m, fmaxf(fmaxf(v[i].x, v[i].y), fmaxf(v[i].z, v[i].w)));
  m = fmaxf(m, __shfl_xor(m, 1));

  float a0 = 0.f, a1 = 0.f, a2 = 0.f, a3 = 0.f;
#pragma unroll
  for (int i = 0; i < 10; i++) {
    a0 += expf(v[i].x - m);
    a1 += expf(v[i].y - m);
    a2 += expf(v[i].z - m);
    a3 += expf(v[i].w - m);
  }
  float s_half = (a0 + a1) + (a2 + a3);
  float s = s_half + __shfl_xor(s_half, 1);
  if (l == 0) scores[row] = 1.0f / s;
}

// ---------------- Kernel 2: fused tail — one block per batch (R17, unchanged) ----
__global__ __launch_bounds__(TT)
void tail_kernel(const float* __restrict__ box, const float* __restrict__ cls,
                 const float* __restrict__ scores,
                 float* __restrict__ out, int N) {
  __shared__ uint32_t lh[NBINS];
  __shared__ uint32_t chs[TT];
  __shared__ unsigned long long sk[CAP];
  __shared__ float sbox[CAP][4];
  __shared__ uint32_t sidx[CAP];
  __shared__ float4 accb[MAXDET];
  __shared__ float4 accp[MAXDET];
  __shared__ uint32_t pick_i[MAXDET];
  __shared__ int T_sh, nacc_sh;
  __shared__ uint32_t lctr;

  const int b = blockIdx.x;
  const int tid = threadIdx.x;
  const float* sc = scores + (size_t)b * N;

#pragma unroll
  for (int j = 0; j < TCHUNK; j++) lh[tid + j * TT] = 0;
  if (tid < CAP) sk[tid] = 0ULL;
  if (tid == 0) { lctr = 0; T_sh = NBINS; }
  __syncthreads();

  const float4* sc4 = (const float4*)sc;
  const int N4 = N >> 2;
  for (int i = tid; i < N4; i += TT) {
    float4 v = sc4[i];
    if (v.x >= 0.05f) atomicAdd(&lh[(__float_as_uint(v.x) >> 12) - BASEKEY], 1u);
    if (v.y >= 0.05f) atomicAdd(&lh[(__float_as_uint(v.y) >> 12) - BASEKEY], 1u);
    if (v.z >= 0.05f) atomicAdd(&lh[(__float_as_uint(v.z) >> 12) - BASEKEY], 1u);
    if (v.w >= 0.05f) atomicAdd(&lh[(__float_as_uint(v.w) >> 12) - BASEKEY], 1u);
  }
  for (int i = (N4 << 2) + tid; i < N; i += TT) {
    float s = sc[i];
    if (s >= 0.05f) atomicAdd(&lh[(__float_as_uint(s) >> 12) - BASEKEY], 1u);
  }
  __syncthreads();

  uint32_t csum = 0;
#pragma unroll
  for (int j = 0; j < TCHUNK; j++) csum += lh[tid * TCHUNK + j];
  chs[tid] = csum;
  __syncthreads();
  for (int off = 1; off < TT; off <<= 1) {
    uint32_t v = chs[tid];
    uint32_t add = (tid + off < TT) ? chs[tid + off] : 0u;
    __syncthreads();
    chs[tid] = v + add;
    __syncthreads();
  }
  {
    uint32_t St = chs[tid];
    uint32_t Sprev = (tid > 0) ? chs[tid - 1] : 0xFFFFFFFFu;
    if (St <= CAP && (tid == 0 || Sprev > CAP)) {
      int T = 0;
      if (tid != 0) {
        uint32_t cum = St;
        int lo = (tid - 1) * TCHUNK;
        T = lo;
        for (int bb = tid * TCHUNK - 1; bb >= lo; bb--) {
          uint32_t nb = cum + lh[bb];
          if (nb > CAP) { T = bb + 1; break; }
          cum = nb;
          if (bb == lo) T = lo;
        }
      }
      T_sh = T;
    }
  }
  __syncthreads();
  const uint32_t T = (uint32_t)T_sh;

  for (int i = tid; i < N4; i += TT) {
    float4 v = sc4[i];
#pragma unroll
    for (int c = 0; c < 4; c++) {
      float s = (c == 0) ? v.x : (c == 1) ? v.y : (c == 2) ? v.z : v.w;
      if (s >= 0.05f) {
        uint32_t key = (__float_as_uint(s) >> 12) - BASEKEY;
        if (key >= T) {
          uint32_t slot = atomicAdd(&lctr, 1u);
          if (slot < CAP)
            sk[slot] = ((unsigned long long)__float_as_uint(s) << 32) |
                       (unsigned long long)(~(uint32_t)(i * 4 + c));
        }
      }
    }
  }
  for (int i = (N4 << 2) + tid; i < N; i += TT) {
    float s = sc[i];
    if (s >= 0.05f) {
      uint32_t key = (__float_as_uint(s) >> 12) - BASEKEY;
      if (key >= T) {
        uint32_t slot = atomicAdd(&lctr, 1u);
        if (slot < CAP)
          sk[slot] = ((unsigned long long)__float_as_uint(s) << 32) |
                     (unsigned long long)(~(uint32_t)i);
      }
    }
  }
  __syncthreads();
  uint32_t nc = lctr; if (nc > CAP) nc = CAP;

  for (int k = 2; k <= CAP; k <<= 1) {
    for (int j = k >> 1; j > 0; j >>= 1) {
      int i = tid;
      if (i < CAP) {
        int ixj = i ^ j;
        if (ixj > i) {
          unsigned long long a = sk[i], c = sk[ixj];
          if (((i & k) == 0) ? (a < c) : (a > c)) { sk[i] = c; sk[ixj] = a; }
        }
      }
      __syncthreads();
    }
  }

  if (tid < CAP) {
    unsigned long long k = sk[tid];
    uint32_t idx = (uint32_t)k ^ 0xFFFFFFFFu;
    sidx[tid] = idx;
    if (k != 0ULL) {
      const float4 f = *(const float4*)(box + ((size_t)b * N + idx) * 4);
      sbox[tid][0] = f.x; sbox[tid][1] = f.y;
      sbox[tid][2] = f.z - f.x; sbox[tid][3] = f.w - f.y;
    } else {
      sbox[tid][0] = 0.f; sbox[tid][1] = 0.f; sbox[tid][2] = 0.f; sbox[tid][3] = 0.f;
    }
  }
  __syncthreads();

  if (tid < 64) {
    const int lane = tid;
    int nacc = 0, nprop = 0;
    for (int cursor = 0; cursor < (int)nc && nacc < MAXDET; cursor += 64) {
      const int c = cursor + lane;
      bool alive = (c < (int)nc);
      float c0 = 0.f, c1 = 0.f, c2 = 0.f, c3 = 0.f;
      uint32_t myidx = 0;
      if (alive) {
        c0 = sbox[c][0]; c1 = sbox[c][1]; c2 = sbox[c][2]; c3 = sbox[c][3];
        myidx = sidx[c];
      }
      const float area_b = (c2 - c0) * (c3 - c1);

#pragma unroll 2
      for (int a = 0; a < nprop; a++) {
        float4 ar = accp[a];
        float area_r = (ar.z - ar.x) * (ar.w - ar.y);
        float ih = fmaxf(0.f, fminf(ar.z, c2) - fmaxf(ar.x, c0));
        float iw = fmaxf(0.f, fminf(ar.w, c3) - fmaxf(ar.y, c1));
        float inter = ih * iw;
        float uni = area_r + area_b - inter;
        bool okk = (area_r > 0.f) && (area_b > 0.f) && (uni > 0.f);
        float iou = okk ? (inter / uni) : 0.f;
        if (iou > 0.5f) alive = false;
      }

      unsigned long long am = __ballot(alive);
      while (am != 0ULL && nacc < MAXDET) {
        int L = (int)(__ffsll(am) - 1);
        float r0 = __shfl(c0, L), r1 = __shfl(c1, L);
        float r2 = __shfl(c2, L), r3 = __shfl(c3, L);
        uint32_t ridx = (uint32_t)__shfl((int)myidx, L);
        bool proper = (r2 > r0) && (r3 > r1);
        if (lane == 0) {
          pick_i[nacc] = ridx;
          accb[nacc] = make_float4(r0, r1, r2, r3);
          if (proper) accp[nprop] = make_float4(r0, r1, r2, r3);
        }
        asm volatile("s_waitcnt lgkmcnt(0)" ::: "memory");
        if (lane == L) alive = false;
        if (proper) {
          if (alive) {
            float area_r = (r2 - r0) * (r3 - r1);
            float ih = fmaxf(0.f, fminf(r2, c2) - fmaxf(r0, c0));
            float iw = fmaxf(0.f, fminf(r3, c3) - fmaxf(r1, c1));
            float inter = ih * iw;
            float uni = area_r + area_b - inter;
            bool okk = (area_r > 0.f) && (area_b > 0.f) && (uni > 0.f);
            float iou = okk ? (inter / uni) : 0.f;
            if (iou > 0.5f) alive = false;
          }
          nprop++;
        }
        am = __ballot(alive);
        nacc++;
      }
    }
    if (lane == 0) nacc_sh = nacc;
  }
  __syncthreads();

  const int nacc = nacc_sh;
  if (tid >= MAXDET) return;
  const int r = b * MAXDET + tid;
  float* boxes_out  = out;
  float* clsidx_out = out + BATCH * MAXDET * 4;
  float* cls_out    = out + BATCH * MAXDET * 4 + BATCH * MAXDET;

  if (tid >= nacc) {
    boxes_out[r * 4 + 0] = 0.f; boxes_out[r * 4 + 1] = 0.f;
    boxes_out[r * 4 + 2] = 0.f; boxes_out[r * 4 + 3] = 0.f;
    clsidx_out[r] = 0.f;
    for (int j = 0; j < NCLS; j++) cls_out[r * NCLS + j] = 0.f;
    return;
  }
  float4 bb = accb[tid];
  boxes_out[r * 4 + 0] = bb.x;
  boxes_out[r * 4 + 1] = bb.y;
  boxes_out[r * 4 + 2] = bb.z;
  boxes_out[r * 4 + 3] = bb.w;

  uint32_t idx = pick_i[tid];
  const float4* p = (const float4*)(cls + ((size_t)b * N + idx) * NCLS);
  float x[NCLS];
#pragma unroll
  for (int i = 0; i < NCLS / 4; i++) {
    float4 v = p[i];
    x[4 * i] = v.x; x[4 * i + 1] = v.y; x[4 * i + 2] = v.z; x[4 * i + 3] = v.w;
  }
  float m = x[0];
#pragma unroll
  for (int i = 1; i < NCLS; i++) m = fmaxf(m, x[i]);
  float r8[8];
#pragma unroll
  for (int j = 0; j < 8; j++) r8[j] = 0.0f;
#pragma unroll
  for (int i = 0; i < NCLS / 8; i++)
#pragma unroll
    for (int j = 0; j < 8; j++) r8[j] += expf(x[i * 8 + j] - m);
  float s = ((r8[0] + r8[1]) + (r8[2] + r8[3])) + ((r8[4] + r8[5]) + (r8[6] + r8[7]));

  float best = -1.f; int bi = 0;
  for (int j = 0; j < NCLS; j++) {
    float pj = expf(x[j] - m) / s;
    cls_out[r * NCLS + j] = pj;
    if (pj > best) { best = pj; bi = j; }
  }
  clsidx_out[r] = (float)bi;
}

extern "C" void kernel_launch(void* const* d_in, const int* in_sizes, int n_in,
                              void* d_out, int out_size, void* d_ws, size_t ws_size,
                              hipStream_t stream) {
  (void)n_in; (void)out_size; (void)ws_size;
  const float* box = (const float*)d_in[0];
  const float* cls = (const float*)d_in[1];
  const int N = in_sizes[0] / (BATCH * 4);
  const int BN = BATCH * N;

  float* ws_scores = (float*)d_ws;   // BN floats

  {
    long long tot = (long long)BN * 2;
    int blocks = (int)((tot + 255) / 256);
    scores_kernel<<<blocks, 256, 0, stream>>>(cls, ws_scores, BN);
  }
  tail_kernel<<<BATCH, TT, 0, stream>>>(box, cls, ws_scores, (float*)d_out, N);
}